// Round 6
// baseline (337.801 us; speedup 1.0000x reference)
//
#include <hip/hip_runtime.h>
#include <math.h>

#define EPS 1e-5f

constexpr int B = 8, S = 1024, E = 512, H = 8;
constexpr int M = B * S;          // 8192 rows

typedef __attribute__((ext_vector_type(8))) short short8;  // 8 bf16 (4 VGPRs)
typedef __attribute__((ext_vector_type(4))) float f32x4;

// fp32 -> bf16 bits, round-to-nearest-even
static __device__ __forceinline__ unsigned short f2bf(float f) {
    unsigned int x = __float_as_uint(f);
    x += 0x7FFFu + ((x >> 16) & 1u);
    return (unsigned short)(x >> 16);
}
static __device__ __forceinline__ float bf2f(unsigned short u) {
    return __uint_as_float(((unsigned int)u) << 16);
}

// async global->LDS, 16B per lane (global_load_lds_dwordx4)
typedef __attribute__((address_space(3))) unsigned int  lds_uint;
typedef __attribute__((address_space(1))) unsigned int  glb_uint;
static __device__ __forceinline__ void gload16(const unsigned short* g, unsigned short* l) {
    __builtin_amdgcn_global_load_lds((const glb_uint*)g, (lds_uint*)l, 16, 0, 0);
}

// ---------------------------------------------------------------------------
// LN -> bf16: one wave per row (E=512, 8 elems/lane), stats via 64-lane shuffles.
// ---------------------------------------------------------------------------
__global__ __launch_bounds__(256) void ln_bf16_kernel(
    const float* __restrict__ x, const float* __restrict__ w,
    const float* __restrict__ bb, unsigned short* __restrict__ out) {
    int row = blockIdx.x * 4 + (threadIdx.x >> 6);
    int lane = threadIdx.x & 63;
    const float* xr = x + (size_t)row * E + lane * 8;
    float4 v0 = *(const float4*)xr;
    float4 v1 = *(const float4*)(xr + 4);
    float vv[8] = {v0.x, v0.y, v0.z, v0.w, v1.x, v1.y, v1.z, v1.w};
    float s = 0.f;
    #pragma unroll
    for (int i = 0; i < 8; i++) s += vv[i];
    #pragma unroll
    for (int o = 1; o < 64; o <<= 1) s += __shfl_xor(s, o);
    float mu = s * (1.0f / E);
    float qs = 0.f;
    #pragma unroll
    for (int i = 0; i < 8; i++) { float d = vv[i] - mu; qs += d * d; }
    #pragma unroll
    for (int o = 1; o < 64; o <<= 1) qs += __shfl_xor(qs, o);
    float rs = rsqrtf(qs * (1.0f / E) + EPS);
    float4 w0 = *(const float4*)(w + lane * 8), w1 = *(const float4*)(w + lane * 8 + 4);
    float4 b0 = *(const float4*)(bb + lane * 8), b1 = *(const float4*)(bb + lane * 8 + 4);
    float ww[8] = {w0.x, w0.y, w0.z, w0.w, w1.x, w1.y, w1.z, w1.w};
    float bv[8] = {b0.x, b0.y, b0.z, b0.w, b1.x, b1.y, b1.z, b1.w};
    short8 o8;
    #pragma unroll
    for (int i = 0; i < 8; i++) o8[i] = (short)f2bf((vv[i] - mu) * rs * ww[i] + bv[i]);
    *(short8*)(out + (size_t)row * E + lane * 8) = o8;
}

// ---------------------------------------------------------------------------
// Full LN (fp32 out) for the final output — wave-per-row.
// ---------------------------------------------------------------------------
__global__ __launch_bounds__(256) void ln_full_kernel(
    const float* __restrict__ x, const float* __restrict__ w,
    const float* __restrict__ bb, float* __restrict__ out) {
    int row = blockIdx.x * 4 + (threadIdx.x >> 6);
    int lane = threadIdx.x & 63;
    const float* xr = x + (size_t)row * E + lane * 8;
    float4 v0 = *(const float4*)xr;
    float4 v1 = *(const float4*)(xr + 4);
    float vv[8] = {v0.x, v0.y, v0.z, v0.w, v1.x, v1.y, v1.z, v1.w};
    float s = 0.f;
    #pragma unroll
    for (int i = 0; i < 8; i++) s += vv[i];
    #pragma unroll
    for (int o = 1; o < 64; o <<= 1) s += __shfl_xor(s, o);
    float mu = s * (1.0f / E);
    float qs = 0.f;
    #pragma unroll
    for (int i = 0; i < 8; i++) { float d = vv[i] - mu; qs += d * d; }
    #pragma unroll
    for (int o = 1; o < 64; o <<= 1) qs += __shfl_xor(qs, o);
    float rs = rsqrtf(qs * (1.0f / E) + EPS);
    float4 w0 = *(const float4*)(w + lane * 8), w1 = *(const float4*)(w + lane * 8 + 4);
    float4 b0 = *(const float4*)(bb + lane * 8), b1 = *(const float4*)(bb + lane * 8 + 4);
    float* op = out + (size_t)row * E + lane * 8;
    float4 o0, o1;
    o0.x = (vv[0] - mu) * rs * w0.x + b0.x;
    o0.y = (vv[1] - mu) * rs * w0.y + b0.y;
    o0.z = (vv[2] - mu) * rs * w0.z + b0.z;
    o0.w = (vv[3] - mu) * rs * w0.w + b0.w;
    o1.x = (vv[4] - mu) * rs * w1.x + b1.x;
    o1.y = (vv[5] - mu) * rs * w1.y + b1.y;
    o1.z = (vv[6] - mu) * rs * w1.z + b1.z;
    o1.w = (vv[7] - mu) * rs * w1.w + b1.w;
    *(float4*)op = o0;
    *(float4*)(op + 4) = o1;
}

// ---------------------------------------------------------------------------
// Weight conversion f32 -> bf16 into one packed buffer: [qkv | o | f]
// ---------------------------------------------------------------------------
__global__ __launch_bounds__(256) void w2bf_kernel(
    const float* __restrict__ wqkv, const float* __restrict__ wo,
    const float* __restrict__ wf, unsigned short* __restrict__ out) {
    int base = (blockIdx.x * 256 + threadIdx.x) * 4;
    float4 v;
    if (base < 3 * E * E)           v = *(const float4*)(wqkv + base);
    else if (base < 4 * E * E)      v = *(const float4*)(wo + (base - 3 * E * E));
    else                            v = *(const float4*)(wf + (base - 4 * E * E));
    ushort4 o;
    o.x = f2bf(v.x); o.y = f2bf(v.y); o.z = f2bf(v.z); o.w = f2bf(v.w);
    *(ushort4*)(out + base) = o;
}

// ---------------------------------------------------------------------------
// bf16 MFMA GEMM (m97 structure): C[M,Ntot] = A[M,512] @ W[Ntot,512]^T + bias
//   OUT_MODE 0: bf16 [M,Ntot]; 1: f32 +residf; 2: f32 +bf16 resid; 3: kv-split
// ---------------------------------------------------------------------------
template <int OUT_MODE>
__global__ __launch_bounds__(256) void gemm_mfma(
    const unsigned short* __restrict__ A, const unsigned short* __restrict__ W,
    const float* __restrict__ bias,
    const float* __restrict__ residf, const unsigned short* __restrict__ residb,
    void* __restrict__ C0, void* __restrict__ C1, int Ntot) {
    __shared__ unsigned short As[128 * 32];
    __shared__ unsigned short Bs[128 * 32];
    const int t = threadIdx.x;
    const int wave = t >> 6, lane = t & 63;
    const int quad = lane >> 4, l16 = lane & 15;
    const int m0 = blockIdx.x * 128, n0 = blockIdx.y * 128;
    const int wm = (wave >> 1) * 64, wn = (wave & 1) * 64;

    const int srow = t >> 2;
    const int skof = (t & 3) * 8;

    f32x4 acc[4][4];
    #pragma unroll
    for (int i = 0; i < 4; i++)
        #pragma unroll
        for (int j = 0; j < 4; j++) acc[i][j] = (f32x4){0.f, 0.f, 0.f, 0.f};

    for (int k0 = 0; k0 < E; k0 += 32) {
        gload16(A + (size_t)(m0 + srow) * E + k0 + skof,        As + t * 8);
        gload16(A + (size_t)(m0 + 64 + srow) * E + k0 + skof,   As + 2048 + t * 8);
        gload16(W + (size_t)(n0 + srow) * E + k0 + skof,        Bs + t * 8);
        gload16(W + (size_t)(n0 + 64 + srow) * E + k0 + skof,   Bs + 2048 + t * 8);
        __syncthreads();
        short8 af[4], bfr[4];
        #pragma unroll
        for (int i = 0; i < 4; i++)
            af[i] = *(const short8*)&As[(wm + i * 16 + l16) * 32 + quad * 8];
        #pragma unroll
        for (int j = 0; j < 4; j++)
            bfr[j] = *(const short8*)&Bs[(wn + j * 16 + l16) * 32 + quad * 8];
        #pragma unroll
        for (int i = 0; i < 4; i++)
            #pragma unroll
            for (int j = 0; j < 4; j++)
                acc[i][j] = __builtin_amdgcn_mfma_f32_16x16x32_bf16(af[i], bfr[j], acc[i][j], 0, 0, 0);
        __syncthreads();
    }

    #pragma unroll
    for (int i = 0; i < 4; i++) {
        const int mrow0 = m0 + wm + i * 16 + quad * 4;
        #pragma unroll
        for (int j = 0; j < 4; j++) {
            const int ncol = n0 + wn + j * 16 + l16;
            const float bval = bias[ncol];
            if (OUT_MODE == 0) {
                #pragma unroll
                for (int r = 0; r < 4; r++)
                    ((unsigned short*)C0)[(size_t)(mrow0 + r) * Ntot + ncol] =
                        f2bf(acc[i][j][r] + bval);
            } else if (OUT_MODE == 1) {
                #pragma unroll
                for (int r = 0; r < 4; r++) {
                    size_t idx = (size_t)(mrow0 + r) * Ntot + ncol;
                    ((float*)C0)[idx] = acc[i][j][r] + bval + residf[idx];
                }
            } else if (OUT_MODE == 2) {
                #pragma unroll
                for (int r = 0; r < 4; r++) {
                    size_t idx = (size_t)(mrow0 + r) * Ntot + ncol;
                    ((float*)C0)[idx] = acc[i][j][r] + bval + bf2f(residb[idx]);
                }
            } else {
                if (ncol < 512) {
                    #pragma unroll
                    for (int r = 0; r < 4; r++)
                        ((unsigned short*)C0)[(size_t)(mrow0 + r) * 512 + ncol] =
                            f2bf(acc[i][j][r] + bval);
                } else {
                    const int nv = ncol - 512;
                    const int b2 = mrow0 >> 10, s0v = mrow0 & 1023;
                    ushort4 o;
                    o.x = f2bf(acc[i][j][0] + bval);
                    o.y = f2bf(acc[i][j][1] + bval);
                    o.z = f2bf(acc[i][j][2] + bval);
                    o.w = f2bf(acc[i][j][3] + bval);
                    *(ushort4*)((unsigned short*)C1 + ((size_t)b2 * 512 + nv) * 1024 + s0v) = o;
                }
            }
        }
    }
}

// ---------------------------------------------------------------------------
// MFMA attention, HPB heads per block. Grid = B*(H/HPB)*(S/16).
// Merged single-pass softmax: local max + exp + local sum BEFORE the one
// reduction barrier; rescale by exp(lmax-gmax)/gsum after. 2 barriers/head.
// aw: HPB==8 -> direct f32 (register accumulation, r5 path);
//     HPB>1  -> bf16 partial plane per head-group (reduce kernel sums);
//     HPB==1 -> bf16 plane written inline (no 64-VGPR accumulator,
//               __launch_bounds__(256,4) -> 4 blocks/CU at 33.8 KB LDS).
// ---------------------------------------------------------------------------
template <int HPB>
__global__ __launch_bounds__(256, (HPB == 1 ? 4 : 2)) void attn_mfma_kernel(
    const unsigned short* __restrict__ q,   // [B][S][E] bf16
    const unsigned short* __restrict__ k,   // [B][S][E] bf16
    const unsigned short* __restrict__ vt,  // [B][E][S] bf16
    unsigned short* __restrict__ ctx,       // [B][S][E] bf16
    unsigned short* __restrict__ awp,       // bf16 planes [H/HPB][B][S][S]
    float* __restrict__ aw) {               // f32 direct (HPB==8 only)
    __shared__ unsigned short s_p[16][1032];
    __shared__ float s_red[2][4][16];       // [max|sum][wave][row]
    constexpr int HG = H / HPB;

    const int t = threadIdx.x;
    const int wave = t >> 6, lane = t & 63;
    const int quad = lane >> 4, l16 = lane & 15;
    const int qt   = blockIdx.x & 63;
    const int rest = blockIdx.x >> 6;
    const int hg   = rest & (HG - 1);
    const int b    = rest / HG;
    const int q0   = qt * 16;
    const size_t qrow = ((size_t)(b * S + q0 + l16)) * E;

    f32x4 awacc[16];
    if (HPB > 1) {
        #pragma unroll
        for (int i = 0; i < 16; i++) awacc[i] = (f32x4){0.f, 0.f, 0.f, 0.f};
    }

    for (int hh = 0; hh < HPB; hh++) {
        const int h = hg * HPB + hh;
        short8 aq0 = *(const short8*)(q + qrow + h * 64 + quad * 8);
        short8 aq1 = *(const short8*)(q + qrow + h * 64 + 32 + quad * 8);

        // ---- scores: 4 batches of 8 deep loads, 16 MFMA pairs ----
        f32x4 sacc[16];
        #pragma unroll
        for (int g = 0; g < 4; g++) {
            short8 kf0[4], kf1[4];
            #pragma unroll
            for (int i = 0; i < 4; i++) {
                const int kcol = wave * 256 + (g * 4 + i) * 16 + l16;
                const unsigned short* kp =
                    k + ((size_t)(b * S + kcol)) * E + h * 64 + quad * 8;
                kf0[i] = *(const short8*)(kp);
                kf1[i] = *(const short8*)(kp + 32);
            }
            #pragma unroll
            for (int i = 0; i < 4; i++) {
                f32x4 c = (f32x4){0.f, 0.f, 0.f, 0.f};
                c = __builtin_amdgcn_mfma_f32_16x16x32_bf16(aq0, kf0[i], c, 0, 0, 0);
                c = __builtin_amdgcn_mfma_f32_16x16x32_bf16(aq1, kf1[i], c, 0, 0, 0);
                sacc[g * 4 + i] = c * 0.125f;
            }
        }

        // ---- local max + exp + local sum (pre-barrier) ----
        float lm[4], ls[4];
        #pragma unroll
        for (int r = 0; r < 4; r++) {
            float mv = sacc[0][r];
            #pragma unroll
            for (int nt = 1; nt < 16; nt++) mv = fmaxf(mv, sacc[nt][r]);
            #pragma unroll
            for (int o = 1; o < 16; o <<= 1) mv = fmaxf(mv, __shfl_xor(mv, o));
            lm[r] = mv;
            ls[r] = 0.f;
        }
        #pragma unroll
        for (int nt = 0; nt < 16; nt++)
            #pragma unroll
            for (int r = 0; r < 4; r++) {
                float e = __expf(sacc[nt][r] - lm[r]);
                sacc[nt][r] = e;
                ls[r] += e;
            }
        #pragma unroll
        for (int r = 0; r < 4; r++) {
            #pragma unroll
            for (int o = 1; o < 16; o <<= 1) ls[r] += __shfl_xor(ls[r], o);
        }
        if (l16 == 0) {
            #pragma unroll
            for (int r = 0; r < 4; r++) {
                s_red[0][wave][quad * 4 + r] = lm[r];
                s_red[1][wave][quad * 4 + r] = ls[r];
            }
        }
        __syncthreads();                                   // (B1)

        // ---- combine: scale = exp(lmax - gmax) / gsum ----
        float scale[4];
        #pragma unroll
        for (int r = 0; r < 4; r++) {
            const int row = quad * 4 + r;
            float m0 = s_red[0][0][row], m1 = s_red[0][1][row];
            float m2 = s_red[0][2][row], m3 = s_red[0][3][row];
            float gmax = fmaxf(fmaxf(m0, m1), fmaxf(m2, m3));
            float gsum = s_red[1][0][row] * __expf(m0 - gmax)
                       + s_red[1][1][row] * __expf(m1 - gmax)
                       + s_red[1][2][row] * __expf(m2 - gmax)
                       + s_red[1][3][row] * __expf(m3 - gmax);
            scale[r] = __expf(lm[r] - gmax) / gsum;
        }

        // ---- normalize, aw handling, write P (bf16) to LDS ----
        #pragma unroll
        for (int nt = 0; nt < 16; nt++) {
            #pragma unroll
            for (int r = 0; r < 4; r++) {
                float p = sacc[nt][r] * scale[r];
                unsigned short pb = f2bf(p);
                if (HPB == 1) {
                    awp[((size_t)((h * B + b) * S + q0 + quad * 4 + r)) * S +
                        wave * 256 + nt * 16 + l16] = pb;
                } else {
                    awacc[nt][r] += p;
                }
                s_p[quad * 4 + r][wave * 256 + nt * 16 + l16] = pb;
            }
        }
        __syncthreads();                                   // (B2)

        // ---- PV: 4 quarters of (8 V-loads + 8 P-ds_reads), 2 accumulators ----
        f32x4 cacc0 = (f32x4){0.f, 0.f, 0.f, 0.f};
        f32x4 cacc1 = (f32x4){0.f, 0.f, 0.f, 0.f};
        const unsigned short* vrow =
            vt + ((size_t)(b * E + h * 64 + wave * 16 + l16)) * S;
        #pragma unroll
        for (int qtr = 0; qtr < 4; qtr++) {
            short8 vf[8], pf[8];
            #pragma unroll
            for (int i = 0; i < 8; i++)
                vf[i] = *(const short8*)(vrow + (qtr * 8 + i) * 32 + quad * 8);
            #pragma unroll
            for (int i = 0; i < 8; i++)
                pf[i] = *(const short8*)(&s_p[l16][(qtr * 8 + i) * 32 + quad * 8]);
            #pragma unroll
            for (int i = 0; i < 8; i += 2) {
                cacc0 = __builtin_amdgcn_mfma_f32_16x16x32_bf16(pf[i],     vf[i],     cacc0, 0, 0, 0);
                cacc1 = __builtin_amdgcn_mfma_f32_16x16x32_bf16(pf[i + 1], vf[i + 1], cacc1, 0, 0, 0);
            }
        }
        f32x4 cacc = cacc0 + cacc1;
        unsigned short* crow = ctx + ((size_t)(b * S + q0)) * E + h * 64 + wave * 16 + l16;
        #pragma unroll
        for (int r = 0; r < 4; r++)
            crow[(size_t)(quad * 4 + r) * E] = f2bf(cacc[r]);
    }

    // ---- final aw write ----
    if (HPB == 8) {
        #pragma unroll
        for (int nt = 0; nt < 16; nt++)
            #pragma unroll
            for (int r = 0; r < 4; r++)
                aw[((size_t)(b * S + q0 + quad * 4 + r)) * S + wave * 256 + nt * 16 + l16] =
                    awacc[nt][r] * (1.0f / H);
    } else if (HPB > 1) {
        #pragma unroll
        for (int nt = 0; nt < 16; nt++)
            #pragma unroll
            for (int r = 0; r < 4; r++)
                awp[((size_t)((hg * B + b) * S + q0 + quad * 4 + r)) * S +
                    wave * 256 + nt * 16 + l16] = f2bf(awacc[nt][r]);
    }
}

// ---------------------------------------------------------------------------
// aw reduce: aw = (1/H) * sum of NP bf16 planes. 8 f32 outputs per thread.
// ---------------------------------------------------------------------------
template <int NP>
__global__ __launch_bounds__(256) void aw_reduce_kernel(
    const unsigned short* __restrict__ awp, float* __restrict__ aw) {
    const size_t PLN = (size_t)B * S * S;
    size_t idx = ((size_t)blockIdx.x * 256 + threadIdx.x) * 8;
    float acc[8] = {};
    #pragma unroll
    for (int p = 0; p < NP; p++) {
        short8 v = *(const short8*)(awp + p * PLN + idx);
        #pragma unroll
        for (int j = 0; j < 8; j++) acc[j] += bf2f((unsigned short)v[j]);
    }
    float4 o0 = make_float4(acc[0] * (1.0f / H), acc[1] * (1.0f / H),
                            acc[2] * (1.0f / H), acc[3] * (1.0f / H));
    float4 o1 = make_float4(acc[4] * (1.0f / H), acc[5] * (1.0f / H),
                            acc[6] * (1.0f / H), acc[7] * (1.0f / H));
    *(float4*)(aw + idx) = o0;
    *(float4*)(aw + idx + 4) = o1;
}

// ---------------------------------------------------------------------------
extern "C" void kernel_launch(void* const* d_in, const int* in_sizes, int n_in,
                              void* d_out, int out_size, void* d_ws, size_t ws_size,
                              hipStream_t stream) {
    const float* Zab  = (const float*)d_in[0];
    const float* Za   = (const float*)d_in[1];
    const float* lnw  = (const float*)d_in[2];
    const float* lnb  = (const float*)d_in[3];
    const float* Wqkv = (const float*)d_in[4];
    const float* bqkv = (const float*)d_in[5];
    const float* Wo   = (const float*)d_in[6];
    const float* bo   = (const float*)d_in[7];
    const float* Wf   = (const float*)d_in[8];
    const float* bf   = (const float*)d_in[9];

    float* out_final = (float*)d_out;
    float* out_aw    = out_final + (size_t)B * S * E;

    char* ws = (char*)d_ws;
    // Static buffers (live through attention):
    unsigned short* qb   = (unsigned short*)(ws);               // [0,8M)
    unsigned short* kb   = (unsigned short*)(ws + (8u << 20));  // [8,16M)
    unsigned short* vtb  = (unsigned short*)(ws + (16u << 20)); // [16,24M)
    unsigned short* ctxb = (unsigned short*)(ws + (24u << 20)); // [24,32M)
    // Pre-attention staging (dead once attention starts):
    unsigned short* aqb  = (unsigned short*)(ws + (32u << 20)); // [32,40M)
    unsigned short* akvb = (unsigned short*)(ws + (40u << 20)); // [40,48M)
    // Post-attention f32 buffers (awp planes consumed by reduce before these):
    float* xb  = (float*)(ws);                                  // [0,16M)
    float* tb  = (float*)(ws + (16u << 20));                    // [16,32M)
    unsigned short* xnb = aqb;                                  // [32,40M)

    const size_t PL  = (size_t)B * S * S * sizeof(unsigned short); // 16 MB/plane
    const size_t WBF = (size_t)5 * E * E * sizeof(unsigned short); // 2.5 MB
    unsigned short* awp = (unsigned short*)(ws + (32ull << 20));

    // Pick heads-per-block by available workspace (fixed per session ->
    // same branch every call; capture-safe).
    int mode;                 // HPB
    unsigned short* wbf;
    if (ws_size >= (32ull << 20) + 8 * PL + WBF) {
        mode = 1; wbf = (unsigned short*)(ws + (32ull << 20) + 8 * PL);
    } else if (ws_size >= (32ull << 20) + 4 * PL + WBF) {
        mode = 2; wbf = (unsigned short*)(ws + (32ull << 20) + 4 * PL);
    } else if (ws_size >= (32ull << 20) + 2 * PL + WBF) {
        mode = 4; wbf = (unsigned short*)(ws + (32ull << 20) + 2 * PL);
    } else {
        mode = 8; wbf = (unsigned short*)(ws + (48ull << 20));  // r5 layout
    }

    dim3 blk(256);

    // 1. weights -> bf16 (packed: qkv | o | f)
    w2bf_kernel<<<(5 * E * E) / 1024, blk, 0, stream>>>(Wqkv, Wo, Wf, wbf);

    // 2. LN(Zab), LN(Za) -> bf16
    ln_bf16_kernel<<<M / 4, blk, 0, stream>>>(Zab, lnw, lnb, aqb);
    ln_bf16_kernel<<<M / 4, blk, 0, stream>>>(Za,  lnw, lnb, akvb);

    // 3. q = LN(Zab)@Wq^T + bq (bf16); kv = LN(Za)@[Wk;Wv]^T + b (K bf16, V^T bf16)
    gemm_mfma<0><<<dim3(M / 128, 4), blk, 0, stream>>>(aqb,  wbf,               bqkv,     nullptr, nullptr, qb, nullptr, 512);
    gemm_mfma<3><<<dim3(M / 128, 8), blk, 0, stream>>>(akvb, wbf + (size_t)E*E, bqkv + E, nullptr, nullptr, kb, vtb, 1024);

    // 4. attention -> ctx (bf16) + aw (planes + reduce, or direct)
    if (mode == 1) {
        attn_mfma_kernel<1><<<B * 8 * 64, blk, 0, stream>>>(qb, kb, vtb, ctxb, awp, nullptr);
        aw_reduce_kernel<8><<<4096, blk, 0, stream>>>(awp, out_aw);
    } else if (mode == 2) {
        attn_mfma_kernel<2><<<B * 4 * 64, blk, 0, stream>>>(qb, kb, vtb, ctxb, awp, nullptr);
        aw_reduce_kernel<4><<<4096, blk, 0, stream>>>(awp, out_aw);
    } else if (mode == 4) {
        attn_mfma_kernel<4><<<B * 2 * 64, blk, 0, stream>>>(qb, kb, vtb, ctxb, awp, nullptr);
        aw_reduce_kernel<2><<<4096, blk, 0, stream>>>(awp, out_aw);
    } else {
        attn_mfma_kernel<8><<<B * 1 * 64, blk, 0, stream>>>(qb, kb, vtb, ctxb, nullptr, out_aw);
    }

    // 5. x = ctx@Wo^T + bo + Zab (f32)
    gemm_mfma<1><<<dim3(M / 128, 4), blk, 0, stream>>>(ctxb, wbf + (size_t)3*E*E, bo, Zab, nullptr, xb, nullptr, 512);

    // 6. xn = LN(x) -> bf16
    ln_bf16_kernel<<<M / 4, blk, 0, stream>>>(xb, lnw, lnb, xnb);

    // 7. t = xn@Wf^T + bf + xn (f32)
    gemm_mfma<2><<<dim3(M / 128, 4), blk, 0, stream>>>(xnb, wbf + (size_t)4*E*E, bf, nullptr, xnb, tb, nullptr, 512);

    // 8. final = LN(t)
    ln_full_kernel<<<M / 4, blk, 0, stream>>>(tb, lnw, lnb, out_final);
}

// Round 7
// 282.765 us; speedup vs baseline: 1.1946x; 1.1946x over previous
//
#include <hip/hip_runtime.h>
#include <math.h>

#define EPS 1e-5f

constexpr int B = 8, S = 1024, E = 512, H = 8;
constexpr int M = B * S;          // 8192 rows

typedef __attribute__((ext_vector_type(8))) short short8;  // 8 bf16 (4 VGPRs)
typedef __attribute__((ext_vector_type(4))) float f32x4;

// fp32 -> bf16 bits, round-to-nearest-even
static __device__ __forceinline__ unsigned short f2bf(float f) {
    unsigned int x = __float_as_uint(f);
    x += 0x7FFFu + ((x >> 16) & 1u);
    return (unsigned short)(x >> 16);
}
static __device__ __forceinline__ float bf2f(unsigned short u) {
    return __uint_as_float(((unsigned int)u) << 16);
}

// async global->LDS, 16B per lane (global_load_lds_dwordx4)
typedef __attribute__((address_space(3))) unsigned int  lds_uint;
typedef __attribute__((address_space(1))) unsigned int  glb_uint;
static __device__ __forceinline__ void gload16(const unsigned short* g, unsigned short* l) {
    __builtin_amdgcn_global_load_lds((const glb_uint*)g, (lds_uint*)l, 16, 0, 0);
}
// s_waitcnt vmcnt(N) only (lgkm=15, exp=7 untouched). m135: in-order drain.
template <int N>
static __device__ __forceinline__ void waitvm() {
    __builtin_amdgcn_s_waitcnt(0x0F70 | N);
}

// ---------------------------------------------------------------------------
// LN -> bf16: one wave per row (E=512, 8 elems/lane), stats via 64-lane shuffles.
// ---------------------------------------------------------------------------
__global__ __launch_bounds__(256) void ln_bf16_kernel(
    const float* __restrict__ x, const float* __restrict__ w,
    const float* __restrict__ bb, unsigned short* __restrict__ out) {
    int row = blockIdx.x * 4 + (threadIdx.x >> 6);
    int lane = threadIdx.x & 63;
    const float* xr = x + (size_t)row * E + lane * 8;
    float4 v0 = *(const float4*)xr;
    float4 v1 = *(const float4*)(xr + 4);
    float vv[8] = {v0.x, v0.y, v0.z, v0.w, v1.x, v1.y, v1.z, v1.w};
    float s = 0.f;
    #pragma unroll
    for (int i = 0; i < 8; i++) s += vv[i];
    #pragma unroll
    for (int o = 1; o < 64; o <<= 1) s += __shfl_xor(s, o);
    float mu = s * (1.0f / E);
    float qs = 0.f;
    #pragma unroll
    for (int i = 0; i < 8; i++) { float d = vv[i] - mu; qs += d * d; }
    #pragma unroll
    for (int o = 1; o < 64; o <<= 1) qs += __shfl_xor(qs, o);
    float rs = rsqrtf(qs * (1.0f / E) + EPS);
    float4 w0 = *(const float4*)(w + lane * 8), w1 = *(const float4*)(w + lane * 8 + 4);
    float4 b0 = *(const float4*)(bb + lane * 8), b1 = *(const float4*)(bb + lane * 8 + 4);
    float ww[8] = {w0.x, w0.y, w0.z, w0.w, w1.x, w1.y, w1.z, w1.w};
    float bv[8] = {b0.x, b0.y, b0.z, b0.w, b1.x, b1.y, b1.z, b1.w};
    short8 o8;
    #pragma unroll
    for (int i = 0; i < 8; i++) o8[i] = (short)f2bf((vv[i] - mu) * rs * ww[i] + bv[i]);
    *(short8*)(out + (size_t)row * E + lane * 8) = o8;
}

// ---------------------------------------------------------------------------
// Full LN (fp32 out) for the final output — wave-per-row.
// ---------------------------------------------------------------------------
__global__ __launch_bounds__(256) void ln_full_kernel(
    const float* __restrict__ x, const float* __restrict__ w,
    const float* __restrict__ bb, float* __restrict__ out) {
    int row = blockIdx.x * 4 + (threadIdx.x >> 6);
    int lane = threadIdx.x & 63;
    const float* xr = x + (size_t)row * E + lane * 8;
    float4 v0 = *(const float4*)xr;
    float4 v1 = *(const float4*)(xr + 4);
    float vv[8] = {v0.x, v0.y, v0.z, v0.w, v1.x, v1.y, v1.z, v1.w};
    float s = 0.f;
    #pragma unroll
    for (int i = 0; i < 8; i++) s += vv[i];
    #pragma unroll
    for (int o = 1; o < 64; o <<= 1) s += __shfl_xor(s, o);
    float mu = s * (1.0f / E);
    float qs = 0.f;
    #pragma unroll
    for (int i = 0; i < 8; i++) { float d = vv[i] - mu; qs += d * d; }
    #pragma unroll
    for (int o = 1; o < 64; o <<= 1) qs += __shfl_xor(qs, o);
    float rs = rsqrtf(qs * (1.0f / E) + EPS);
    float4 w0 = *(const float4*)(w + lane * 8), w1 = *(const float4*)(w + lane * 8 + 4);
    float4 b0 = *(const float4*)(bb + lane * 8), b1 = *(const float4*)(bb + lane * 8 + 4);
    float* op = out + (size_t)row * E + lane * 8;
    float4 o0, o1;
    o0.x = (vv[0] - mu) * rs * w0.x + b0.x;
    o0.y = (vv[1] - mu) * rs * w0.y + b0.y;
    o0.z = (vv[2] - mu) * rs * w0.z + b0.z;
    o0.w = (vv[3] - mu) * rs * w0.w + b0.w;
    o1.x = (vv[4] - mu) * rs * w1.x + b1.x;
    o1.y = (vv[5] - mu) * rs * w1.y + b1.y;
    o1.z = (vv[6] - mu) * rs * w1.z + b1.z;
    o1.w = (vv[7] - mu) * rs * w1.w + b1.w;
    *(float4*)op = o0;
    *(float4*)(op + 4) = o1;
}

// ---------------------------------------------------------------------------
// Weight conversion f32 -> bf16 into one packed buffer: [qkv | o | f]
// ---------------------------------------------------------------------------
__global__ __launch_bounds__(256) void w2bf_kernel(
    const float* __restrict__ wqkv, const float* __restrict__ wo,
    const float* __restrict__ wf, unsigned short* __restrict__ out) {
    int base = (blockIdx.x * 256 + threadIdx.x) * 4;
    float4 v;
    if (base < 3 * E * E)           v = *(const float4*)(wqkv + base);
    else if (base < 4 * E * E)      v = *(const float4*)(wo + (base - 3 * E * E));
    else                            v = *(const float4*)(wf + (base - 4 * E * E));
    ushort4 o;
    o.x = f2bf(v.x); o.y = f2bf(v.y); o.z = f2bf(v.z); o.w = f2bf(v.w);
    *(ushort4*)(out + base) = o;
}

// ---------------------------------------------------------------------------
// bf16 MFMA GEMM (m97 structure): C[M,Ntot] = A[M,512] @ W[Ntot,512]^T + bias
//   OUT_MODE 0: bf16 [M,Ntot]; 1: f32 +residf; 2: f32 +bf16 resid; 3: kv-split
// ---------------------------------------------------------------------------
template <int OUT_MODE>
__global__ __launch_bounds__(256) void gemm_mfma(
    const unsigned short* __restrict__ A, const unsigned short* __restrict__ W,
    const float* __restrict__ bias,
    const float* __restrict__ residf, const unsigned short* __restrict__ residb,
    void* __restrict__ C0, void* __restrict__ C1, int Ntot) {
    __shared__ unsigned short As[128 * 32];
    __shared__ unsigned short Bs[128 * 32];
    const int t = threadIdx.x;
    const int wave = t >> 6, lane = t & 63;
    const int quad = lane >> 4, l16 = lane & 15;
    const int m0 = blockIdx.x * 128, n0 = blockIdx.y * 128;
    const int wm = (wave >> 1) * 64, wn = (wave & 1) * 64;

    const int srow = t >> 2;
    const int skof = (t & 3) * 8;

    f32x4 acc[4][4];
    #pragma unroll
    for (int i = 0; i < 4; i++)
        #pragma unroll
        for (int j = 0; j < 4; j++) acc[i][j] = (f32x4){0.f, 0.f, 0.f, 0.f};

    for (int k0 = 0; k0 < E; k0 += 32) {
        gload16(A + (size_t)(m0 + srow) * E + k0 + skof,        As + t * 8);
        gload16(A + (size_t)(m0 + 64 + srow) * E + k0 + skof,   As + 2048 + t * 8);
        gload16(W + (size_t)(n0 + srow) * E + k0 + skof,        Bs + t * 8);
        gload16(W + (size_t)(n0 + 64 + srow) * E + k0 + skof,   Bs + 2048 + t * 8);
        __syncthreads();
        short8 af[4], bfr[4];
        #pragma unroll
        for (int i = 0; i < 4; i++)
            af[i] = *(const short8*)&As[(wm + i * 16 + l16) * 32 + quad * 8];
        #pragma unroll
        for (int j = 0; j < 4; j++)
            bfr[j] = *(const short8*)&Bs[(wn + j * 16 + l16) * 32 + quad * 8];
        #pragma unroll
        for (int i = 0; i < 4; i++)
            #pragma unroll
            for (int j = 0; j < 4; j++)
                acc[i][j] = __builtin_amdgcn_mfma_f32_16x16x32_bf16(af[i], bfr[j], acc[i][j], 0, 0, 0);
        __syncthreads();
    }

    #pragma unroll
    for (int i = 0; i < 4; i++) {
        const int mrow0 = m0 + wm + i * 16 + quad * 4;
        #pragma unroll
        for (int j = 0; j < 4; j++) {
            const int ncol = n0 + wn + j * 16 + l16;
            const float bval = bias[ncol];
            if (OUT_MODE == 0) {
                #pragma unroll
                for (int r = 0; r < 4; r++)
                    ((unsigned short*)C0)[(size_t)(mrow0 + r) * Ntot + ncol] =
                        f2bf(acc[i][j][r] + bval);
            } else if (OUT_MODE == 1) {
                #pragma unroll
                for (int r = 0; r < 4; r++) {
                    size_t idx = (size_t)(mrow0 + r) * Ntot + ncol;
                    ((float*)C0)[idx] = acc[i][j][r] + bval + residf[idx];
                }
            } else if (OUT_MODE == 2) {
                #pragma unroll
                for (int r = 0; r < 4; r++) {
                    size_t idx = (size_t)(mrow0 + r) * Ntot + ncol;
                    ((float*)C0)[idx] = acc[i][j][r] + bval + bf2f(residb[idx]);
                }
            } else {
                if (ncol < 512) {
                    #pragma unroll
                    for (int r = 0; r < 4; r++)
                        ((unsigned short*)C0)[(size_t)(mrow0 + r) * 512 + ncol] =
                            f2bf(acc[i][j][r] + bval);
                } else {
                    const int nv = ncol - 512;
                    const int b2 = mrow0 >> 10, s0v = mrow0 & 1023;
                    ushort4 o;
                    o.x = f2bf(acc[i][j][0] + bval);
                    o.y = f2bf(acc[i][j][1] + bval);
                    o.z = f2bf(acc[i][j][2] + bval);
                    o.w = f2bf(acc[i][j][3] + bval);
                    *(ushort4*)((unsigned short*)C1 + ((size_t)b2 * 512 + nv) * 1024 + s0v) = o;
                }
            }
        }
    }
}

// ---------------------------------------------------------------------------
// MFMA attention v2: wave-private DMA staging of K and V (coalesced
// global_load_lds, XOR-swizzled LDS layout -> 2-way-max bank aliasing on
// ds_read_b128), 2-deep chunk prefetch gated by explicit s_waitcnt vmcnt(N).
// No barriers for staging (each wave reads only LDS it DMA'd itself); 3
// barriers/head for softmax reduce + P round-trip. HPB=2 heads per block,
// aw accumulated in registers per head-group -> 4 bf16 planes + reduce.
// Grid = B * (H/2) * 64 = 2048 blocks.
// ---------------------------------------------------------------------------
__global__ __launch_bounds__(256, 2) void attn_mfma_kernel(
    const unsigned short* __restrict__ q,   // [B][S][E] bf16
    const unsigned short* __restrict__ k,   // [B][S][E] bf16
    const unsigned short* __restrict__ vt,  // [B][E][S] bf16
    unsigned short* __restrict__ ctx,       // [B][S][E] bf16
    unsigned short* __restrict__ awp) {     // bf16 planes [4][B][S][S]
    __shared__ unsigned short s_mem[16 * 1032]; // P (16x1032) | K-staging union
    __shared__ unsigned short s_v[4 * 2048];    // V staging: 4 waves x 2 bufs x 1024
    __shared__ float s_red[2][4][16];

    const int t = threadIdx.x;
    const int wave = t >> 6, lane = t & 63;
    const int quad = lane >> 4, l16 = lane & 15;
    const int qt   = blockIdx.x & 63;
    const int rest = blockIdx.x >> 6;
    const int hg   = rest & 3;              // head group (2 heads each)
    const int b    = rest >> 2;
    const int q0   = qt * 16;
    const size_t qrow = ((size_t)(b * S + q0 + l16)) * E;

    // wave-private staging areas (shorts)
    unsigned short* karea = s_mem + wave * 4128;   // 2 bufs x 2048 (32 rows x 64)
    unsigned short* varea = s_v + wave * 2048;     // 2 bufs x 1024 (16 rows x 64)

    // DMA lane mapping: dest = base + lane*8 shorts (HW rule); XOR source swizzle
    const int dr = lane >> 3;               // row within 8-row group
    const int dc = lane & 7;                // dest 16B col-block
    const int csrc = dc ^ dr;               // swizzled source col-block
    const int sw7 = l16 & 7;                // read-side swizzle key

    f32x4 awacc[16];
    #pragma unroll
    for (int i = 0; i < 16; i++) awacc[i] = (f32x4){0.f, 0.f, 0.f, 0.f};

    for (int hh = 0; hh < 2; hh++) {
        const int h = hg * 2 + hh;

        // K chunk c (32 rows of wave's k-range) -> buf
        auto stage_k = [&](int c, int buf) {
            const unsigned short* src =
                k + ((size_t)(b * S + wave * 256 + c * 32 + dr)) * E + h * 64 + csrc * 8;
            unsigned short* dst = karea + buf * 2048 + dr * 64 + dc * 8;
            gload16(src,                  dst);
            gload16(src + (size_t)8 * E,  dst + 512);
            gload16(src + (size_t)16 * E, dst + 1024);
            gload16(src + (size_t)24 * E, dst + 1536);
        };
        // V chunk cv (64 s-cols of wave's 16 d-rows) -> buf
        auto stage_v = [&](int cv, int buf) {
            const unsigned short* src =
                vt + ((size_t)(b * E + h * 64 + wave * 16 + dr)) * S + cv * 64 + csrc * 8;
            unsigned short* dst = varea + buf * 1024 + dr * 64 + dc * 8;
            gload16(src,                 dst);
            gload16(src + (size_t)8 * S, dst + 512);
        };

        short8 aq0 = *(const short8*)(q + qrow + h * 64 + quad * 8);
        short8 aq1 = *(const short8*)(q + qrow + h * 64 + 32 + quad * 8);

        // ---- scores: 8 staged K chunks, 2-deep prefetch ----
        f32x4 sacc[16];
        stage_k(0, 0);
        stage_k(1, 1);
        #pragma unroll
        for (int c = 0; c < 8; c++) {
            if (c < 7) waitvm<4>(); else waitvm<0>();
            const unsigned short* kbuf = karea + (c & 1) * 2048;
            #pragma unroll
            for (int ntl = 0; ntl < 2; ntl++) {
                const int rl = ntl * 16 + l16;
                short8 kf0 = *(const short8*)(kbuf + rl * 64 + ((quad)     ^ sw7) * 8);
                short8 kf1 = *(const short8*)(kbuf + rl * 64 + ((4 + quad) ^ sw7) * 8);
                f32x4 cc = (f32x4){0.f, 0.f, 0.f, 0.f};
                cc = __builtin_amdgcn_mfma_f32_16x16x32_bf16(aq0, kf0, cc, 0, 0, 0);
                cc = __builtin_amdgcn_mfma_f32_16x16x32_bf16(aq1, kf1, cc, 0, 0, 0);
                sacc[c * 2 + ntl] = cc * 0.125f;
            }
            if (c < 6) stage_k(c + 2, c & 1);
        }

        // ---- merged single-pass softmax: local max+exp+sum pre-barrier ----
        float lm[4], ls[4];
        #pragma unroll
        for (int r = 0; r < 4; r++) {
            float mv = sacc[0][r];
            #pragma unroll
            for (int nt = 1; nt < 16; nt++) mv = fmaxf(mv, sacc[nt][r]);
            #pragma unroll
            for (int o = 1; o < 16; o <<= 1) mv = fmaxf(mv, __shfl_xor(mv, o));
            lm[r] = mv;
            ls[r] = 0.f;
        }
        #pragma unroll
        for (int nt = 0; nt < 16; nt++)
            #pragma unroll
            for (int r = 0; r < 4; r++) {
                float e = __expf(sacc[nt][r] - lm[r]);
                sacc[nt][r] = e;
                ls[r] += e;
            }
        #pragma unroll
        for (int r = 0; r < 4; r++) {
            #pragma unroll
            for (int o = 1; o < 16; o <<= 1) ls[r] += __shfl_xor(ls[r], o);
        }
        if (l16 == 0) {
            #pragma unroll
            for (int r = 0; r < 4; r++) {
                s_red[0][wave][quad * 4 + r] = lm[r];
                s_red[1][wave][quad * 4 + r] = ls[r];
            }
        }
        __syncthreads();                                   // (B1) also: all K reads done
        float scale[4];
        #pragma unroll
        for (int r = 0; r < 4; r++) {
            const int row = quad * 4 + r;
            float m0 = s_red[0][0][row], m1 = s_red[0][1][row];
            float m2 = s_red[0][2][row], m3 = s_red[0][3][row];
            float gmax = fmaxf(fmaxf(m0, m1), fmaxf(m2, m3));
            float gsum = s_red[1][0][row] * __expf(m0 - gmax)
                       + s_red[1][1][row] * __expf(m1 - gmax)
                       + s_red[1][2][row] * __expf(m2 - gmax)
                       + s_red[1][3][row] * __expf(m3 - gmax);
            scale[r] = __expf(lm[r] - gmax) / gsum;
        }

        // ---- normalize, accumulate aw, write P (bf16) into s_mem [16][1032] ----
        #pragma unroll
        for (int nt = 0; nt < 16; nt++) {
            #pragma unroll
            for (int r = 0; r < 4; r++) {
                float p = sacc[nt][r] * scale[r];
                awacc[nt][r] += p;
                s_mem[(quad * 4 + r) * 1032 + wave * 256 + nt * 16 + l16] = f2bf(p);
            }
        }
        __syncthreads();                                   // (B2) P visible

        // ---- PV: 16 staged V chunks, 2-deep prefetch; P from s_mem ----
        f32x4 cacc0 = (f32x4){0.f, 0.f, 0.f, 0.f};
        f32x4 cacc1 = (f32x4){0.f, 0.f, 0.f, 0.f};
        stage_v(0, 0);
        stage_v(1, 1);
        #pragma unroll
        for (int cv = 0; cv < 16; cv++) {
            if (cv < 15) waitvm<2>(); else waitvm<0>();
            const unsigned short* vbuf = varea + (cv & 1) * 1024;
            short8 vf0 = *(const short8*)(vbuf + l16 * 64 + ((quad)     ^ sw7) * 8);
            short8 vf1 = *(const short8*)(vbuf + l16 * 64 + ((4 + quad) ^ sw7) * 8);
            short8 pf0 = *(const short8*)(s_mem + l16 * 1032 + cv * 64 + quad * 8);
            short8 pf1 = *(const short8*)(s_mem + l16 * 1032 + cv * 64 + 32 + quad * 8);
            cacc0 = __builtin_amdgcn_mfma_f32_16x16x32_bf16(pf0, vf0, cacc0, 0, 0, 0);
            cacc1 = __builtin_amdgcn_mfma_f32_16x16x32_bf16(pf1, vf1, cacc1, 0, 0, 0);
            if (cv < 14) stage_v(cv + 2, cv & 1);
        }
        f32x4 cacc = cacc0 + cacc1;
        unsigned short* crow = ctx + ((size_t)(b * S + q0)) * E + h * 64 + wave * 16 + l16;
        #pragma unroll
        for (int r = 0; r < 4; r++)
            crow[(size_t)(quad * 4 + r) * E] = f2bf(cacc[r]);
        __syncthreads();                                   // (B3) P reads done -> K restage safe
    }

    // ---- head-group partial plane (bf16) ----
    #pragma unroll
    for (int nt = 0; nt < 16; nt++) {
        #pragma unroll
        for (int r = 0; r < 4; r++)
            awp[((size_t)((hg * B + b) * S + q0 + quad * 4 + r)) * S +
                wave * 256 + nt * 16 + l16] = f2bf(awacc[nt][r]);
    }
}

// ---------------------------------------------------------------------------
// aw reduce: aw = (1/H) * sum of NP bf16 planes. 8 f32 outputs per thread.
// ---------------------------------------------------------------------------
template <int NP>
__global__ __launch_bounds__(256) void aw_reduce_kernel(
    const unsigned short* __restrict__ awp, float* __restrict__ aw) {
    const size_t PLN = (size_t)B * S * S;
    size_t idx = ((size_t)blockIdx.x * 256 + threadIdx.x) * 8;
    float acc[8] = {};
    #pragma unroll
    for (int p = 0; p < NP; p++) {
        short8 v = *(const short8*)(awp + p * PLN + idx);
        #pragma unroll
        for (int j = 0; j < 8; j++) acc[j] += bf2f((unsigned short)v[j]);
    }
    float4 o0 = make_float4(acc[0] * (1.0f / H), acc[1] * (1.0f / H),
                            acc[2] * (1.0f / H), acc[3] * (1.0f / H));
    float4 o1 = make_float4(acc[4] * (1.0f / H), acc[5] * (1.0f / H),
                            acc[6] * (1.0f / H), acc[7] * (1.0f / H));
    *(float4*)(aw + idx) = o0;
    *(float4*)(aw + idx + 4) = o1;
}

// ---------------------------------------------------------------------------
extern "C" void kernel_launch(void* const* d_in, const int* in_sizes, int n_in,
                              void* d_out, int out_size, void* d_ws, size_t ws_size,
                              hipStream_t stream) {
    const float* Zab  = (const float*)d_in[0];
    const float* Za   = (const float*)d_in[1];
    const float* lnw  = (const float*)d_in[2];
    const float* lnb  = (const float*)d_in[3];
    const float* Wqkv = (const float*)d_in[4];
    const float* bqkv = (const float*)d_in[5];
    const float* Wo   = (const float*)d_in[6];
    const float* bo   = (const float*)d_in[7];
    const float* Wf   = (const float*)d_in[8];
    const float* bf   = (const float*)d_in[9];

    float* out_final = (float*)d_out;
    float* out_aw    = out_final + (size_t)B * S * E;

    char* ws = (char*)d_ws;
    // Static buffers (live through attention):
    unsigned short* qb   = (unsigned short*)(ws);               // [0,8M)
    unsigned short* kb   = (unsigned short*)(ws + (8u << 20));  // [8,16M)
    unsigned short* vtb  = (unsigned short*)(ws + (16u << 20)); // [16,24M)
    unsigned short* ctxb = (unsigned short*)(ws + (24u << 20)); // [24,32M)
    // Pre-attention staging (dead once attention starts):
    unsigned short* aqb  = (unsigned short*)(ws + (32u << 20)); // [32,40M)
    unsigned short* akvb = (unsigned short*)(ws + (40u << 20)); // [40,48M)
    // awp planes: 4 x 16 MB at [32,96M) (aqb/akvb dead by attention)
    unsigned short* awp  = (unsigned short*)(ws + (32ull << 20));
    unsigned short* wbf  = (unsigned short*)(ws + (96ull << 20)); // 2.5 MB
    // Post-attention f32 buffers:
    float* xb  = (float*)(ws);                                  // [0,16M)
    float* tb  = (float*)(ws + (16u << 20));                    // [16,32M)
    unsigned short* xnb = aqb;                                  // [32,40M) after reduce

    dim3 blk(256);

    // 1. weights -> bf16 (packed: qkv | o | f)
    w2bf_kernel<<<(5 * E * E) / 1024, blk, 0, stream>>>(Wqkv, Wo, Wf, wbf);

    // 2. LN(Zab), LN(Za) -> bf16
    ln_bf16_kernel<<<M / 4, blk, 0, stream>>>(Zab, lnw, lnb, aqb);
    ln_bf16_kernel<<<M / 4, blk, 0, stream>>>(Za,  lnw, lnb, akvb);

    // 3. q = LN(Zab)@Wq^T + bq (bf16); kv = LN(Za)@[Wk;Wv]^T + b (K bf16, V^T bf16)
    gemm_mfma<0><<<dim3(M / 128, 4), blk, 0, stream>>>(aqb,  wbf,               bqkv,     nullptr, nullptr, qb, nullptr, 512);
    gemm_mfma<3><<<dim3(M / 128, 8), blk, 0, stream>>>(akvb, wbf + (size_t)E*E, bqkv + E, nullptr, nullptr, kb, vtb, 1024);

    // 4. attention (staged K/V) -> ctx (bf16) + 4 partial planes; reduce planes
    attn_mfma_kernel<<<B * 4 * 64, blk, 0, stream>>>(qb, kb, vtb, ctxb, awp);
    aw_reduce_kernel<4><<<4096, blk, 0, stream>>>(awp, out_aw);

    // 5. x = ctx@Wo^T + bo + Zab (f32)
    gemm_mfma<1><<<dim3(M / 128, 4), blk, 0, stream>>>(ctxb, wbf + (size_t)3*E*E, bo, Zab, nullptr, xb, nullptr, 512);

    // 6. xn = LN(x) -> bf16
    ln_bf16_kernel<<<M / 4, blk, 0, stream>>>(xb, lnw, lnb, xnb);

    // 7. t = xn@Wf^T + bf + xn (f32)
    gemm_mfma<2><<<dim3(M / 128, 4), blk, 0, stream>>>(xnb, wbf + (size_t)4*E*E, bf, nullptr, xnb, tb, nullptr, 512);

    // 8. final = LN(t)
    ln_full_kernel<<<M / 4, blk, 0, stream>>>(tb, lnw, lnb, out_final);
}